// Round 1
// baseline (576.094 us; speedup 1.0000x reference)
//
#include <hip/hip_runtime.h>
#include <hip/hip_bf16.h>

#define BB 64
#define SS 2048
#define DD 512
#define UU 512
#define BS (BB*SS)   // 131072

typedef __attribute__((ext_vector_type(8))) short bf16x8;
typedef __attribute__((ext_vector_type(4))) float f32x4;

static __device__ __forceinline__ unsigned short f2bf(float x) {
    union { float f; unsigned int u; } v; v.f = x;
    unsigned int r = v.u + 0x7FFFu + ((v.u >> 16) & 1u);
    return (unsigned short)(r >> 16);
}

// ---- W2 [D][U] fp32  ->  W2T [U][D] bf16 (transposed) ----
__global__ void k_w2t(const float* __restrict__ W2, unsigned short* __restrict__ W2T) {
    __shared__ float tile[64][65];
    const int ti = blockIdx.x >> 3;   // d-tile
    const int tj = blockIdx.x & 7;    // u-tile
    const int t = threadIdx.x;
    #pragma unroll
    for (int i = 0; i < 16; ++i) {
        int e = i*256 + t;
        int dr = e >> 6, uc = e & 63;
        tile[dr][uc] = W2[(size_t)(ti*64+dr)*UU + tj*64+uc];
    }
    __syncthreads();
    #pragma unroll
    for (int i = 0; i < 16; ++i) {
        int e = i*256 + t;
        int ur = e >> 6, dc = e & 63;
        W2T[(size_t)(tj*64+ur)*DD + ti*64+dc] = f2bf(tile[dc][ur]);
    }
}

// ---- qpb[b][u] = sum_d query[b][d]*W1[d][u] + b1[u] + b2[u]  (fp32) ----
__global__ void k_qproj(const float* __restrict__ query, const float* __restrict__ W1,
                        const float* __restrict__ b1, const float* __restrict__ b2,
                        float* __restrict__ qpb) {
    const int b = blockIdx.x, t = threadIdx.x;
    float a0 = 0.f, a1 = 0.f;
    for (int d = 0; d < DD; ++d) {
        float q = query[b*DD + d];
        a0 += q * W1[(size_t)d*UU + t];
        a1 += q * W1[(size_t)d*UU + t + 256];
    }
    qpb[b*UU + t]       = a0 + b1[t]     + b2[t];
    qpb[b*UU + t + 256] = a1 + b1[t+256] + b2[t+256];
}

// ---- fused scores: v_proj GEMM (bf16 MFMA) + tanh + dot(V), scores pre-zeroed ----
__launch_bounds__(256, 2)
__global__ void k_scores(const float* __restrict__ values,
                         const unsigned short* __restrict__ W2T,
                         const float* __restrict__ qpb,
                         const float* __restrict__ Vw,
                         float* __restrict__ scores) {
    // 64 rows x 512 k of bf16 A-tile, XOR-swizzled in 16B granules: exactly 64 KB
    __shared__ unsigned short Albuf[64*512];
    const int t  = threadIdx.x;
    const int m0 = blockIdx.x * 64;        // global row base (b,s flattened)
    const int b  = m0 >> 11;               // 2048 rows per batch

    // stage A: fp32 -> bf16, swizzle granule g -> g ^ (row&7)
    const float* src = values + (size_t)m0 * DD;
    #pragma unroll
    for (int i = 0; i < 16; ++i) {
        int gf  = i*256 + t;               // granule 0..4095
        int row = gf >> 6;                 // 0..63
        int g   = gf & 63;                 // granule in row (8 bf16 each)
        const float4 f0 = *(const float4*)(src + (size_t)row*DD + g*8);
        const float4 f1 = *(const float4*)(src + (size_t)row*DD + g*8 + 4);
        ushort4 lo, hi;
        lo.x = f2bf(f0.x); lo.y = f2bf(f0.y); lo.z = f2bf(f0.z); lo.w = f2bf(f0.w);
        hi.x = f2bf(f1.x); hi.y = f2bf(f1.y); hi.z = f2bf(f1.z); hi.w = f2bf(f1.w);
        int gs = g ^ (row & 7);
        ushort4* dst = (ushort4*)&Albuf[row*512 + gs*8];
        dst[0] = lo; dst[1] = hi;
    }
    __syncthreads();

    const int wave = t >> 6, lane = t & 63;
    const int ln15 = lane & 15, quad = lane >> 4;

    float sacc[4][4] = {};                 // [mt][r] running score partials

    for (int nc = 0; nc < 2; ++nc) {       // two 256-wide n-chunks
        const int nwb = nc*256 + wave*64;  // this wave's n base
        f32x4 acc[4][4];
        #pragma unroll
        for (int mt = 0; mt < 4; ++mt)
            #pragma unroll
            for (int nt = 0; nt < 4; ++nt)
                acc[mt][nt] = f32x4{0.f, 0.f, 0.f, 0.f};

        #pragma unroll 2
        for (int k0 = 0; k0 < DD; k0 += 32) {
            const int kq = k0 + quad*8;
            bf16x8 bfr[4], afr[4];
            #pragma unroll
            for (int nt = 0; nt < 4; ++nt) {
                int n = nwb + nt*16 + ln15;
                bfr[nt] = *(const bf16x8*)(W2T + (size_t)n*DD + kq);
            }
            #pragma unroll
            for (int mt = 0; mt < 4; ++mt) {
                int m = mt*16 + ln15;
                int g = (kq >> 3) ^ (m & 7);
                afr[mt] = *(const bf16x8*)&Albuf[m*512 + g*8];
            }
            #pragma unroll
            for (int mt = 0; mt < 4; ++mt)
                #pragma unroll
                for (int nt = 0; nt < 4; ++nt)
                    acc[mt][nt] = __builtin_amdgcn_mfma_f32_16x16x32_bf16(
                        afr[mt], bfr[nt], acc[mt][nt], 0, 0, 0);
        }

        // epilogue: h = tanh(qpb + vproj); sacc += h * V[n]
        #pragma unroll
        for (int nt = 0; nt < 4; ++nt) {
            int n = nwb + nt*16 + ln15;
            float qv = qpb[b*UU + n];
            float vw = Vw[n];
            #pragma unroll
            for (int mt = 0; mt < 4; ++mt)
                #pragma unroll
                for (int r = 0; r < 4; ++r) {
                    float x = qv + acc[mt][nt][r];
                    float e = __expf(x + x);
                    float h = 1.f - 2.f / (e + 1.f);   // tanh(x), inf-safe
                    sacc[mt][r] += h * vw;
                }
        }
    }

    // reduce over the 16 lanes of each quad (they share output rows)
    #pragma unroll
    for (int mt = 0; mt < 4; ++mt)
        #pragma unroll
        for (int r = 0; r < 4; ++r) {
            float v = sacc[mt][r];
            v += __shfl_xor(v, 1);
            v += __shfl_xor(v, 2);
            v += __shfl_xor(v, 4);
            v += __shfl_xor(v, 8);
            if (ln15 == 0)
                atomicAdd(&scores[m0 + mt*16 + quad*4 + r], v);
        }
}

// ---- softmax over S per batch ----
__global__ void k_softmax(const float* __restrict__ scores, float* __restrict__ wts) {
    __shared__ float red[64];
    const int b = blockIdx.x, t = threadIdx.x;
    const float* s = scores + b*SS;
    float v[8];
    float mx = -1e30f;
    #pragma unroll
    for (int i = 0; i < 8; ++i) { v[i] = s[i*256 + t]; mx = fmaxf(mx, v[i]); }
    #pragma unroll
    for (int off = 32; off; off >>= 1) mx = fmaxf(mx, __shfl_xor(mx, off));
    if ((t & 63) == 0) red[t >> 6] = mx;
    __syncthreads();
    mx = fmaxf(fmaxf(red[0], red[1]), fmaxf(red[2], red[3]));
    float sum = 0.f;
    #pragma unroll
    for (int i = 0; i < 8; ++i) { v[i] = __expf(v[i] - mx); sum += v[i]; }
    #pragma unroll
    for (int off = 32; off; off >>= 1) sum += __shfl_xor(sum, off);
    __syncthreads();
    if ((t & 63) == 0) red[t >> 6] = sum;
    __syncthreads();
    sum = red[0] + red[1] + red[2] + red[3];
    float inv = 1.f / sum;
    #pragma unroll
    for (int i = 0; i < 8; ++i) wts[b*SS + i*256 + t] = v[i] * inv;
}

// ---- context[b][d] = sum_s wts[b][s] * values[b][s][d] ----
__launch_bounds__(256)
__global__ void k_context(const float* __restrict__ values, const float* __restrict__ wts,
                          float* __restrict__ out) {
    __shared__ float4 red[16][16];
    const int blk = blockIdx.x;
    const int b = blk >> 3, d0 = (blk & 7) * 64;
    const int t = threadIdx.x;
    const int di = t & 15, sg = t >> 4;
    float4 acc = make_float4(0.f, 0.f, 0.f, 0.f);
    const float* vb = values + (size_t)b*SS*DD + d0 + di*4;
    const float* wb = wts + b*SS;
    #pragma unroll 4
    for (int s = sg; s < SS; s += 16) {
        float w = wb[s];
        float4 v = *(const float4*)(vb + (size_t)s*DD);
        acc.x += w*v.x; acc.y += w*v.y; acc.z += w*v.z; acc.w += w*v.w;
    }
    red[sg][di] = acc;
    __syncthreads();
    if (t < 16) {
        float4 sum = make_float4(0.f, 0.f, 0.f, 0.f);
        #pragma unroll
        for (int g = 0; g < 16; ++g) {
            float4 v = red[g][t];
            sum.x += v.x; sum.y += v.y; sum.z += v.z; sum.w += v.w;
        }
        *(float4*)(out + (size_t)b*DD + d0 + t*4) = sum;
    }
}

extern "C" void kernel_launch(void* const* d_in, const int* in_sizes, int n_in,
                              void* d_out, int out_size, void* d_ws, size_t ws_size,
                              hipStream_t stream) {
    const float* query  = (const float*)d_in[0];
    const float* values = (const float*)d_in[1];
    const float* W1     = (const float*)d_in[2];
    const float* b1     = (const float*)d_in[3];
    const float* W2     = (const float*)d_in[4];
    const float* b2     = (const float*)d_in[5];
    const float* Vw     = (const float*)d_in[6];
    // d_in[7] = bv: softmax over s is shift-invariant -> no-op

    char* ws = (char*)d_ws;
    unsigned short* W2T = (unsigned short*)ws;                         // 512 KB
    float* qpb    = (float*)(ws + 524288);                             // 128 KB
    float* scores = (float*)(ws + 524288 + 131072);                    // 512 KB
    float* wts    = (float*)(ws + 524288 + 131072 + 524288);           // 512 KB
    float* out    = (float*)d_out;

    hipMemsetAsync(scores, 0, BS * sizeof(float), stream);
    k_w2t<<<64, 256, 0, stream>>>(W2, W2T);
    k_qproj<<<BB, 256, 0, stream>>>(query, W1, b1, b2, qpb);
    k_scores<<<BS/64, 256, 0, stream>>>(values, W2T, qpb, Vw, scores);
    k_softmax<<<BB, 256, 0, stream>>>(scores, wts);
    k_context<<<BB*8, 256, 0, stream>>>(values, wts, out);
}